// Round 1
// baseline (453.332 us; speedup 1.0000x reference)
//
#include <hip/hip_runtime.h>
#include <hip/hip_bf16.h>

#define Bdim 64
#define Tdim 96
#define Pdim 256
#define Hdim 128
#define Gdim 512   // 4*H
#define Odim 24
#define WROW 132   // h row length in bf16 elements (128 + 4 pad -> 264B rows, 8B aligned)

typedef __bf16 bf16x8 __attribute__((ext_vector_type(8)));
typedef float  f32x16 __attribute__((ext_vector_type(16)));

union BF8 { uint2 u2[2]; unsigned short s[8]; bf16x8 v; };

__device__ __forceinline__ unsigned short f2bf(float f) {
    unsigned int u = __float_as_uint(f);
    u = (u + 0x7FFFu + ((u >> 16) & 1u)) >> 16;   // RNE
    return (unsigned short)u;
}
__device__ __forceinline__ float bf2f(unsigned short s) {
    return __uint_as_float(((unsigned int)s) << 16);
}
__device__ __forceinline__ float sigm(float x) {
    return __builtin_amdgcn_rcpf(1.0f + __expf(-x));
}
__device__ __forceinline__ float tanh_fast(float x) {
    return __builtin_fmaf(2.0f, sigm(2.0f * x), -1.0f);
}

// One block per point p. 8 waves; wave w owns r' rows [64w, 64w+64) (16 hidden units),
// all 64 batches. r' = 4*k + gate (gate order i,f,g,o), so the 32x32 MFMA C/D layout
// puts all 4 gates of one (b,k) into regs 4q..4q+3 of one lane.
__global__ __launch_bounds__(512, 2)
void lstm_fused(const float* __restrict__ x,
                const float* __restrict__ W_ih,
                const float* __restrict__ W_hh,
                const float* __restrict__ b_ih,
                const float* __restrict__ b_hh,
                const float* __restrict__ W_fc,
                const float* __restrict__ b_fc,
                float* __restrict__ out)
{
    __shared__ unsigned short hlds[Bdim * WROW];  // h state, bf16
    __shared__ float wihl[Gdim];                  // W_ih permuted to r'
    __shared__ float gbl[Gdim];                   // b_ih + b_hh permuted to r'

    const int p   = blockIdx.x;
    const int tid = threadIdx.x;
    const int w   = tid >> 6;    // wave 0..7
    const int l   = tid & 63;
    const int l31 = l & 31;
    const int hi  = l >> 5;

    // ---- stage permuted W_ih and combined bias ----
    {
        int r = tid;             // 512 threads == Gdim
        int orow = ((r & 3) << 7) | (r >> 2);   // gate*128 + k
        wihl[r] = W_ih[(size_t)p * Gdim + orow];
        gbl[r]  = b_ih[(size_t)p * Gdim + orow] + b_hh[(size_t)p * Gdim + orow];
    }
    for (int i = tid; i < Bdim * WROW; i += 512) hlds[i] = 0;

    // ---- preload A fragments (W_hh, bf16) into registers; time-invariant ----
    // A[m=r'][k]: lane holds k = 16*ks + 8*hi + j, row m = 64w + 32mt + l31
    bf16x8 afr[2][8];
    {
        const float* wp = W_hh + (size_t)p * Gdim * Hdim;
        #pragma unroll
        for (int mt = 0; mt < 2; ++mt) {
            int m = w * 64 + mt * 32 + l31;          // r'
            int orow = ((m & 3) << 7) | (m >> 2);    // original gate-major row
            const float* rowp = wp + orow * Hdim;
            #pragma unroll
            for (int ks = 0; ks < 8; ++ks) {
                int k0 = ks * 16 + hi * 8;
                float4 va = *(const float4*)(rowp + k0);
                float4 vb = *(const float4*)(rowp + k0 + 4);
                BF8 u;
                u.s[0] = f2bf(va.x); u.s[1] = f2bf(va.y);
                u.s[2] = f2bf(va.z); u.s[3] = f2bf(va.w);
                u.s[4] = f2bf(vb.x); u.s[5] = f2bf(vb.y);
                u.s[6] = f2bf(vb.z); u.s[7] = f2bf(vb.w);
                afr[mt][ks] = u.v;
            }
        }
    }

    __syncthreads();

    // ---- per-lane gx coefficients: acc element (mt, j) -> r' = 64w+32mt+(j&3)+8*(j>>2)+4*hi
    float wihr[2][16], gbr[2][16];
    #pragma unroll
    for (int mt = 0; mt < 2; ++mt)
        #pragma unroll
        for (int j = 0; j < 16; ++j) {
            int rp = w * 64 + mt * 32 + (j & 3) + ((j >> 2) << 3) + (hi << 2);
            wihr[mt][j] = wihl[rp];
            gbr[mt][j]  = gbl[rp];
        }

    float cre[2][2][4];
    #pragma unroll
    for (int mt = 0; mt < 2; ++mt)
        for (int nt = 0; nt < 2; ++nt)
            for (int q = 0; q < 4; ++q) cre[mt][nt][q] = 0.f;

    const float* xp = x + p;     // x[b][t][p] at ((b*T+t)*P + p)
    float xv0 = xp[(size_t)(l31 * Tdim) * Pdim];
    float xv1 = xp[(size_t)((l31 + 32) * Tdim) * Pdim];

    for (int t = 0; t < Tdim; ++t) {
        float xn0 = 0.f, xn1 = 0.f;
        if (t + 1 < Tdim) {
            xn0 = xp[(size_t)(l31 * Tdim + t + 1) * Pdim];
            xn1 = xp[(size_t)((l31 + 32) * Tdim + t + 1) * Pdim];
        }

        // init acc with gx = x*W_ih + (b_ih+b_hh)
        f32x16 acc[2][2];
        #pragma unroll
        for (int mt = 0; mt < 2; ++mt)
            #pragma unroll
            for (int j = 0; j < 16; ++j) {
                acc[mt][0][j] = __builtin_fmaf(xv0, wihr[mt][j], gbr[mt][j]);
                acc[mt][1][j] = __builtin_fmaf(xv1, wihr[mt][j], gbr[mt][j]);
            }

        // GEMM: D[r'][b] += W[r'][k] * h[b][k], K=128 in 8 steps of 16
        #pragma unroll
        for (int ks = 0; ks < 8; ++ks) {
            int boff = ks * 32 + hi * 16;   // byte offset of k0 in a 264B row
            BF8 b0, b1;
            const char* hbase = (const char*)hlds;
            b0.u2[0] = *(const uint2*)(hbase + l31 * (WROW * 2) + boff);
            b0.u2[1] = *(const uint2*)(hbase + l31 * (WROW * 2) + boff + 8);
            b1.u2[0] = *(const uint2*)(hbase + (l31 + 32) * (WROW * 2) + boff);
            b1.u2[1] = *(const uint2*)(hbase + (l31 + 32) * (WROW * 2) + boff + 8);
            acc[0][0] = __builtin_amdgcn_mfma_f32_32x32x16_bf16(afr[0][ks], b0.v, acc[0][0], 0, 0, 0);
            acc[0][1] = __builtin_amdgcn_mfma_f32_32x32x16_bf16(afr[0][ks], b1.v, acc[0][1], 0, 0, 0);
            acc[1][0] = __builtin_amdgcn_mfma_f32_32x32x16_bf16(afr[1][ks], b0.v, acc[1][0], 0, 0, 0);
            acc[1][1] = __builtin_amdgcn_mfma_f32_32x32x16_bf16(afr[1][ks], b1.v, acc[1][1], 0, 0, 0);
        }

        __syncthreads();   // all h reads done before overwrite

        // epilogue: regs 4q..4q+3 of lane = gates i,f,g,o of (b = 32nt+l31, k = 16w+8mt+2q+hi)
        #pragma unroll
        for (int mt = 0; mt < 2; ++mt)
            #pragma unroll
            for (int nt = 0; nt < 2; ++nt)
                #pragma unroll
                for (int q = 0; q < 4; ++q) {
                    float iv = sigm(acc[mt][nt][4 * q + 0]);
                    float fv = sigm(acc[mt][nt][4 * q + 1]);
                    float gv = tanh_fast(acc[mt][nt][4 * q + 2]);
                    float ov = sigm(acc[mt][nt][4 * q + 3]);
                    float c  = __builtin_fmaf(fv, cre[mt][nt][q], iv * gv);
                    cre[mt][nt][q] = c;
                    float hv = ov * tanh_fast(c);
                    int k = w * 16 + mt * 8 + q * 2 + hi;
                    int b = nt * 32 + l31;
                    hlds[b * WROW + k] = f2bf(hv);
                }

        __syncthreads();   // h writes visible before next step's reads
        xv0 = xn0; xv1 = xn1;
    }

    // ---- FC: out[b][o][p] = sum_k W_fc[p][o][k]*h[b][k] + b_fc[p][o] ----
    const float* wfc = W_fc + (size_t)p * Odim * Hdim;
    const float* bfc = b_fc + (size_t)p * Odim;
    for (int i = tid; i < Bdim * Odim; i += 512) {
        int o = i % Odim;
        int b = i / Odim;
        float s = bfc[o];
        const float* wr = wfc + o * Hdim;
        const unsigned short* hr = hlds + b * WROW;
        #pragma unroll 8
        for (int k2 = 0; k2 < Hdim; ++k2)
            s = __builtin_fmaf(wr[k2], bf2f(hr[k2]), s);
        out[(size_t)b * Odim * Pdim + (size_t)o * Pdim + p] = s;
    }
}

extern "C" void kernel_launch(void* const* d_in, const int* in_sizes, int n_in,
                              void* d_out, int out_size, void* d_ws, size_t ws_size,
                              hipStream_t stream) {
    const float* x    = (const float*)d_in[0];
    const float* W_ih = (const float*)d_in[1];
    const float* W_hh = (const float*)d_in[2];
    const float* b_ih = (const float*)d_in[3];
    const float* b_hh = (const float*)d_in[4];
    const float* W_fc = (const float*)d_in[5];
    const float* b_fc = (const float*)d_in[6];
    float* out = (float*)d_out;

    lstm_fused<<<dim3(Pdim), dim3(512), 0, stream>>>(x, W_ih, W_hh, b_ih, b_hh, W_fc, b_fc, out);
}

// Round 2
// 400.934 us; speedup vs baseline: 1.1307x; 1.1307x over previous
//
#include <hip/hip_runtime.h>
#include <hip/hip_bf16.h>

#define Bdim 64
#define Tdim 96
#define Pdim 256
#define Hdim 128
#define Gdim 512   // 4*H
#define Odim 24
#define WROW 132   // h row length in bf16 elements (128 + 4 pad -> 264B rows, 8B aligned, 66 dw ≡ 2 mod 32 -> 2-way (free) bank pattern)

typedef __bf16 bf16x8 __attribute__((ext_vector_type(8)));
typedef float  f32x16 __attribute__((ext_vector_type(16)));

union BF8 { uint2 u2[2]; unsigned short s[8]; bf16x8 v; };

__device__ __forceinline__ unsigned short f2bf(float f) {
    unsigned int u = __float_as_uint(f);
    u = (u + 0x7FFFu + ((u >> 16) & 1u)) >> 16;   // RNE
    return (unsigned short)u;
}
__device__ __forceinline__ float bf2f(unsigned short s) {
    return __uint_as_float(((unsigned int)s) << 16);
}
__device__ __forceinline__ float exp2_fast(float x) {
#if __has_builtin(__builtin_amdgcn_exp2f)
    return __builtin_amdgcn_exp2f(x);
#else
    return __expf(x * 0.6931471805599453f);
#endif
}
// sigmoid given y = x*log2e (weights pre-scaled): rcp(1 + 2^-y); neg is a free input modifier
__device__ __forceinline__ float sigm2(float y) {
    return __builtin_amdgcn_rcpf(1.0f + exp2_fast(-y));
}

// One block per point p. 16 waves (1024 thr); wave w owns r' rows [32w, 32w+32)
// (8 hidden units x 4 gates), all 64 batches via two MFMAs (nt).
// r' = 4*k + gate (i,f,g,o): all 4 gates of one (b,k) land in regs 4q..4q+3 of one lane.
// gx (x*W_ih + bias) is fused as a 9th MFMA K-step: A=[W_ih*s, bias*s, 0...], B=[bf(x), 1, 0...].
// All gate rows prescaled by log2e (2*log2e for g); cell state kept in 2*log2e-scaled domain.
__global__ __launch_bounds__(1024, 4)
void lstm_fused(const float* __restrict__ x,
                const float* __restrict__ W_ih,
                const float* __restrict__ W_hh,
                const float* __restrict__ b_ih,
                const float* __restrict__ b_hh,
                const float* __restrict__ W_fc,
                const float* __restrict__ b_fc,
                float* __restrict__ out)
{
    __shared__ unsigned short hl[2][Bdim * WROW];  // double-buffered h state, bf16

    const int p   = blockIdx.x;
    const int tid = threadIdx.x;
    const int w   = tid >> 6;    // wave 0..15
    const int l   = tid & 63;
    const int l31 = l & 31;
    const int hi  = l >> 5;

    const float L1 = 1.4426950408889634f;  // log2(e)

    // zero both h buffers (h0 = 0; buffer 1 fully rewritten before first read, but cheap)
    for (int i = tid; i < 2 * Bdim * WROW; i += 1024) ((unsigned short*)hl)[i] = 0;

    // ---- preload A fragments (time-invariant): W_hh rows + gx row, prescaled ----
    bf16x8 afr[9];
    {
        const int rp   = w * 32 + l31;               // r'
        const int orow = ((rp & 3) << 7) | (rp >> 2); // gate*128 + k
        const float sc = ((rp & 3) == 2) ? (2.0f * L1) : L1;  // g gate: 2*log2e
        const float* rowp = W_hh + (size_t)p * Gdim * Hdim + (size_t)orow * Hdim;
        #pragma unroll
        for (int ks = 0; ks < 8; ++ks) {
            int k0 = ks * 16 + hi * 8;
            float4 va = *(const float4*)(rowp + k0);
            float4 vb = *(const float4*)(rowp + k0 + 4);
            BF8 u;
            u.s[0] = f2bf(sc * va.x); u.s[1] = f2bf(sc * va.y);
            u.s[2] = f2bf(sc * va.z); u.s[3] = f2bf(sc * va.w);
            u.s[4] = f2bf(sc * vb.x); u.s[5] = f2bf(sc * vb.y);
            u.s[6] = f2bf(sc * vb.z); u.s[7] = f2bf(sc * vb.w);
            afr[ks] = u.v;
        }
        BF8 u9;
        #pragma unroll
        for (int j = 0; j < 8; ++j) u9.s[j] = 0;
        if (hi == 0) {
            u9.s[0] = f2bf(sc * W_ih[(size_t)p * Gdim + orow]);                       // k=128
            u9.s[1] = f2bf(sc * (b_ih[(size_t)p * Gdim + orow] +
                                 b_hh[(size_t)p * Gdim + orow]));                     // k=129
        }
        afr[8] = u9.v;
    }

    float cre[2][4];   // scaled-domain cell state
    #pragma unroll
    for (int nt = 0; nt < 2; ++nt)
        #pragma unroll
        for (int q = 0; q < 4; ++q) cre[nt][q] = 0.f;

    const float* xp = x + p;     // x[b][t][p] at ((b*T+t)*P + p)
    float xv0 = xp[(size_t)(l31 * Tdim) * Pdim];
    float xv1 = xp[(size_t)((l31 + 32) * Tdim) * Pdim];

    __syncthreads();

    int cur = 0;
    for (int t = 0; t < Tdim; ++t) {
        float xn0 = 0.f, xn1 = 0.f;
        if (t + 1 < Tdim) {
            xn0 = xp[(size_t)(l31 * Tdim + t + 1) * Pdim];
            xn1 = xp[(size_t)((l31 + 32) * Tdim + t + 1) * Pdim];
        }

        f32x16 acc[2];
        #pragma unroll
        for (int j = 0; j < 16; ++j) { acc[0][j] = 0.f; acc[1][j] = 0.f; }

        // GEMM: D[r'][b] += W[r'][k] * h[b][k], K=128 in 8 steps of 16
        const char* hbase = (const char*)hl[cur];
        #pragma unroll
        for (int ks = 0; ks < 8; ++ks) {
            int boff = ks * 32 + hi * 16;
            BF8 b0, b1;
            b0.u2[0] = *(const uint2*)(hbase + l31 * (WROW * 2) + boff);
            b0.u2[1] = *(const uint2*)(hbase + l31 * (WROW * 2) + boff + 8);
            b1.u2[0] = *(const uint2*)(hbase + (l31 + 32) * (WROW * 2) + boff);
            b1.u2[1] = *(const uint2*)(hbase + (l31 + 32) * (WROW * 2) + boff + 8);
            acc[0] = __builtin_amdgcn_mfma_f32_32x32x16_bf16(afr[ks], b0.v, acc[0], 0, 0, 0);
            acc[1] = __builtin_amdgcn_mfma_f32_32x32x16_bf16(afr[ks], b1.v, acc[1], 0, 0, 0);
        }
        // 9th K-step: gx = x*W_ih + bias, B built in registers
        {
            BF8 b0, b1;
            #pragma unroll
            for (int j = 0; j < 8; ++j) { b0.s[j] = 0; b1.s[j] = 0; }
            unsigned short onebf = hi ? (unsigned short)0 : (unsigned short)0x3F80;
            b0.s[0] = hi ? (unsigned short)0 : f2bf(xv0);
            b0.s[1] = onebf;
            b1.s[0] = hi ? (unsigned short)0 : f2bf(xv1);
            b1.s[1] = onebf;
            acc[0] = __builtin_amdgcn_mfma_f32_32x32x16_bf16(afr[8], b0.v, acc[0], 0, 0, 0);
            acc[1] = __builtin_amdgcn_mfma_f32_32x32x16_bf16(afr[8], b1.v, acc[1], 0, 0, 0);
        }

        // epilogue -> writes h_{t+1} into the OTHER buffer (no read/write barrier needed)
        unsigned short* hw = hl[cur ^ 1];
        #pragma unroll
        for (int nt = 0; nt < 2; ++nt) {
            #pragma unroll
            for (int q = 0; q < 4; ++q) {
                float iv = sigm2(acc[nt][4 * q + 0]);
                float fv = sigm2(acc[nt][4 * q + 1]);
                float ug = sigm2(acc[nt][4 * q + 2]);               // sigma(2*xg), input prescaled 2L
                float gp = __builtin_fmaf(4.0f * L1, ug, -2.0f * L1); // 2L*tanh(xg)
                float ov = sigm2(acc[nt][4 * q + 3]);
                float c  = __builtin_fmaf(fv, cre[nt][q], iv * gp);  // scaled-domain c
                cre[nt][q] = c;
                float v  = __builtin_amdgcn_rcpf(1.0f + exp2_fast(-c)); // sigma(2c_real)
                float th = __builtin_fmaf(2.0f, v, -1.0f);              // tanh(c_real)
                float hv = ov * th;
                int k = w * 8 + 2 * q + hi;
                int b = l31 + 32 * nt;
                hw[b * WROW + k] = f2bf(hv);
            }
        }

        __syncthreads();   // h_{t+1} writes visible; all reads of hl[cur] long since consumed
        cur ^= 1;
        xv0 = xn0; xv1 = xn1;
    }

    // ---- FC: out[b][o][p] = sum_k W_fc[p][o][k]*h[b][k] + b_fc[p][o] ----
    const float* wfc = W_fc + (size_t)p * Odim * Hdim;
    const float* bfc = b_fc + (size_t)p * Odim;
    const unsigned short* hf = hl[cur];
    for (int i = tid; i < Bdim * Odim; i += 1024) {
        int o = i % Odim;
        int b = i / Odim;
        float s = bfc[o];
        const float* wr = wfc + o * Hdim;
        const unsigned short* hr = hf + b * WROW;
        #pragma unroll 8
        for (int k2 = 0; k2 < Hdim; ++k2)
            s = __builtin_fmaf(wr[k2], bf2f(hr[k2]), s);
        out[(size_t)b * Odim * Pdim + (size_t)o * Pdim + p] = s;
    }
}

extern "C" void kernel_launch(void* const* d_in, const int* in_sizes, int n_in,
                              void* d_out, int out_size, void* d_ws, size_t ws_size,
                              hipStream_t stream) {
    const float* x    = (const float*)d_in[0];
    const float* W_ih = (const float*)d_in[1];
    const float* W_hh = (const float*)d_in[2];
    const float* b_ih = (const float*)d_in[3];
    const float* b_hh = (const float*)d_in[4];
    const float* W_fc = (const float*)d_in[5];
    const float* b_fc = (const float*)d_in[6];
    float* out = (float*)d_out;

    lstm_fused<<<dim3(Pdim), dim3(1024), 0, stream>>>(x, W_ih, W_hh, b_ih, b_hh, W_fc, b_fc, out);
}